// Round 6
// baseline (150.591 us; speedup 1.0000x reference)
//
#include <hip/hip_runtime.h>
#include <cfloat>

typedef unsigned short u16;
typedef u16   u16x4 __attribute__((ext_vector_type(4)));
typedef float f32x4 __attribute__((ext_vector_type(4)));
typedef _Float16 f16x8 __attribute__((ext_vector_type(8)));

template <int N> struct ic { static constexpr int value = N; };

#define GL2LDS(gp, lp) __builtin_amdgcn_global_load_lds(                      \
    (const __attribute__((address_space(1))) void*)(gp),                      \
    (__attribute__((address_space(3))) void*)(lp), 16, 0, 0)

__device__ __forceinline__ void f32_to_f16pair(float f, u16& hi, u16& lo) {
  _Float16 h = (_Float16)f;               // RNE
  _Float16 l = (_Float16)(f - (float)h);  // residual (exact subtraction)
  hi = __builtin_bit_cast(u16, h);
  lo = __builtin_bit_cast(u16, l);
}

// Pretile a [R,512] fp32 matrix into f16 hi/lo panels.
// Panel unit: (tile of 256 rows, K-step s of 32 cols) = 32768 bytes.
// Row layout inside a unit: 128 B = [hi: 32 f16 | lo: 32 f16], byte offset
// XOR-swizzled with ((r&7)<<4) — exact LDS image for linear global_load_lds.
__global__ __launch_bounds__(128) void vq_prep(
    const float* __restrict__ src, u16* __restrict__ pan,
    float* __restrict__ sq, float* __restrict__ copy_out) {
  __shared__ float red[2];
  const int row_g = blockIdx.x;
  const int t = threadIdx.x;             // 0..127, 4 floats each
  float4 v = reinterpret_cast<const float4*>(src + (size_t)row_g * 512)[t];
  if (copy_out)
    reinterpret_cast<float4*>(copy_out + (size_t)row_g * 512)[t] = v;
  u16 hi[4], lo[4];
  float f[4] = {v.x, v.y, v.z, v.w};
  #pragma unroll
  for (int i = 0; i < 4; ++i) f32_to_f16pair(f[i], hi[i], lo[i]);
  const int d = t * 4;
  const int tile = row_g >> 8, r = row_g & 255;
  const int s = d >> 5, c = d & 31;
  const size_t pbase = ((size_t)tile * 16 + s) * 32768;
  const unsigned swz = ((unsigned)(r & 7)) << 4;
  const unsigned bh = ((unsigned)(r * 128 + c * 2)) ^ swz;
  const unsigned bl = ((unsigned)(r * 128 + 64 + c * 2)) ^ swz;
  u16x4 th = {hi[0], hi[1], hi[2], hi[3]};
  u16x4 tl = {lo[0], lo[1], lo[2], lo[3]};
  *reinterpret_cast<u16x4*>((char*)pan + pbase + bh) = th;
  *reinterpret_cast<u16x4*>((char*)pan + pbase + bl) = tl;
  if (sq) {
    float ssum = v.x*v.x + v.y*v.y + v.z*v.z + v.w*v.w;
    #pragma unroll
    for (int m = 1; m < 64; m <<= 1) ssum += __shfl_xor(ssum, m);
    if ((t & 63) == 0) red[t >> 6] = ssum;
    __syncthreads();
    if (t == 0) sq[row_g] = red[0] + red[1];
  }
}

// Distance GEMM + per-tile argmin. Tile 256x256, BK=32, 8 waves (2x4),
// per-wave 128x64, mfma 16x16x32_f16 hi/lo 3-term split.
// ONE barrier per K-step, mid-step; per-wave software pipeline:
//   top : stage(s+1) -> other buf (8 gl2lds)
//   sec0: read V<-cur.B[p^1] | MFMA X*U  (Q(p,p))
//   sec1: read Y<-cur.A[p^1] | MFMA X*V  (Q(p,p^1))
//         vmcnt(0) lgkmcnt(0); s_barrier      <-- all cur reads done
//   sec2: read X<-nxt.A[p]   | MFMA Y*U  (Q(p^1,p))
//   sec3: read U<-nxt.B[p]   | MFMA Y*V  (Q(p^1,p^1))
// Gray-order quadrants make every read target dead registers; reads of a
// section overlap the MFMAs of the same section on separate pipes; wave
// parity p=wid&1 staggers operand fetch across waves.
template <int INLINE_A>
__global__ __launch_bounds__(512, 2) void vq_gemm(
    const float* __restrict__ X,
    const u16* __restrict__ Apan, const u16* __restrict__ Bpan,
    const float* __restrict__ c2,
    float2* __restrict__ part, int nnt) {
  __shared__ u16 sA0[16384], sA1[16384], sB0[16384], sB1[16384];
  const int tid = threadIdx.x;
  const int lane = tid & 63, wid = tid >> 6;   // 8 waves
  const int wm = wid >> 2, wn = wid & 3;       // 2 x 4
  const int nwg = gridDim.x;
  const int bid = blockIdx.x;
  const int swb = (bid & 7) * (nwg >> 3) + (bid >> 3);
  const int mtile = swb / nnt, ntile = swb % nnt;
  const int lrow = lane & 15, kgrp = lane >> 4;
  f32x4 acc[8][4] = {};

  #define SCHED0 __builtin_amdgcn_sched_barrier(0)

  auto stageFullA = [&](u16* dst, int s) {
    const char* g = (const char*)Apan + ((size_t)mtile * 16 + s) * 32768;
    #pragma unroll
    for (int i = 0; i < 4; ++i) {
      const int off = i * 8192 + wid * 1024;
      GL2LDS(g + off + lane * 16, (char*)dst + off);
    }
  };
  auto stageFullB = [&](u16* dst, int s) {
    const char* g = (const char*)Bpan + ((size_t)ntile * 16 + s) * 32768;
    #pragma unroll
    for (int i = 0; i < 4; ++i) {
      const int off = i * 8192 + wid * 1024;
      GL2LDS(g + off + lane * 16, (char*)dst + off);
    }
  };
  auto inlineA = [&](u16* dst, int s) {     // fallback: convert X tile into LDS
    const float* ga = X + ((size_t)mtile * 256) * 512 + s * 32;
    #pragma unroll
    for (int p = 0; p < 4; ++p) {
      const int cch = tid + p * 512;
      const int r = cch >> 3, c0 = (cch & 7) * 4;
      float4 v = *reinterpret_cast<const float4*>(ga + (size_t)r * 512 + c0);
      u16 hi[4], lo[4];
      float f[4] = {v.x, v.y, v.z, v.w};
      #pragma unroll
      for (int i2 = 0; i2 < 4; ++i2) f32_to_f16pair(f[i2], hi[i2], lo[i2]);
      const unsigned swz = ((unsigned)(r & 7)) << 4;
      const unsigned bh = ((unsigned)(r * 128 + c0 * 2)) ^ swz;
      const unsigned bl = ((unsigned)(r * 128 + 64 + c0 * 2)) ^ swz;
      u16x4 th = {hi[0], hi[1], hi[2], hi[3]};
      u16x4 tl = {lo[0], lo[1], lo[2], lo[3]};
      *reinterpret_cast<u16x4*>((char*)dst + bh) = th;
      *reinterpret_cast<u16x4*>((char*)dst + bl) = tl;
    }
  };

  auto readA = [&](const u16* buf, int rh, f16x8* h, f16x8* l) {
    #pragma unroll
    for (int t = 0; t < 4; ++t) {
      const int ar = rh * 128 + wm * 64 + t * 16 + lrow;
      const unsigned swz = ((unsigned)(ar & 7)) << 4;
      const unsigned a0 = (unsigned)(ar * 128 + kgrp * 16);
      h[t] = *reinterpret_cast<const f16x8*>((const char*)buf + (a0 ^ swz));
      l[t] = *reinterpret_cast<const f16x8*>((const char*)buf + ((a0 + 64) ^ swz));
    }
  };
  auto readB = [&](const u16* buf, int ch, f16x8* h, f16x8* l) {
    #pragma unroll
    for (int u = 0; u < 2; ++u) {
      const int br = ch * 128 + wn * 32 + u * 16 + lrow;
      const unsigned swz = ((unsigned)(br & 7)) << 4;
      const unsigned b0 = (unsigned)(br * 128 + kgrp * 16);
      h[u] = *reinterpret_cast<const f16x8*>((const char*)buf + (b0 ^ swz));
      l[u] = *reinterpret_cast<const f16x8*>((const char*)buf + ((b0 + 64) ^ swz));
    }
  };

  auto kloop = [&](auto PC) {
    constexpr int P = decltype(PC)::value;
    f16x8 Xh[4], Xl[4], Yh[4], Yl[4];      // A[P], A[P^1]
    f16x8 Uh[2], Ul[2], Vh[2], Vl[2];      // B[P], B[P^1]

    auto MF = [&](auto RH, auto CH, const f16x8* ah, const f16x8* al,
                  const f16x8* bh, const f16x8* bl) {
      constexpr int rh = decltype(RH)::value, ch = decltype(CH)::value;
      __builtin_amdgcn_s_setprio(1);
      #pragma unroll
      for (int t = 0; t < 4; ++t) {
        #pragma unroll
        for (int u = 0; u < 2; ++u) {
          f32x4 a = acc[rh * 4 + t][ch * 2 + u];
          a = __builtin_amdgcn_mfma_f32_16x16x32_f16(ah[t], bh[u], a, 0, 0, 0);
          a = __builtin_amdgcn_mfma_f32_16x16x32_f16(ah[t], bl[u], a, 0, 0, 0);
          a = __builtin_amdgcn_mfma_f32_16x16x32_f16(al[t], bh[u], a, 0, 0, 0);
          acc[rh * 4 + t][ch * 2 + u] = a;
        }
      }
      __builtin_amdgcn_s_setprio(0);
    };

    auto kstep = [&](const u16* Ac, const u16* Bc, u16* An, u16* Bn,
                     int s, bool more) {
      // ---- top: stage next step into the other buffer
      if (more) {
        if constexpr (INLINE_A) { stageFullB(Bn, s + 1); inlineA(An, s + 1); }
        else { stageFullA(An, s + 1); stageFullB(Bn, s + 1); }
      }
      SCHED0;
      // ---- sec0
      readB(Bc, P ^ 1, Vh, Vl);
      SCHED0;
      MF(ic<P>{}, ic<P>{}, Xh, Xl, Uh, Ul);
      SCHED0;
      // ---- sec1
      readA(Ac, P ^ 1, Yh, Yl);
      SCHED0;
      MF(ic<P>{}, ic<P ^ 1>{}, Xh, Xl, Vh, Vl);
      SCHED0;
      // ---- mid-step boundary: all cur-buffer reads issued & drained
      asm volatile("s_waitcnt vmcnt(0) lgkmcnt(0)" ::: "memory");
      __builtin_amdgcn_s_barrier();
      asm volatile("" ::: "memory");
      SCHED0;
      // ---- sec2 (reads target NEXT buffer, just made visible)
      if (more) readA(An, P, Xh, Xl);
      SCHED0;
      MF(ic<P ^ 1>{}, ic<P>{}, Yh, Yl, Uh, Ul);
      SCHED0;
      // ---- sec3
      if (more) readB(Bn, P, Uh, Ul);
      SCHED0;
      MF(ic<P ^ 1>{}, ic<P ^ 1>{}, Yh, Yl, Vh, Vl);
      SCHED0;
    };

    // prologue prereads (buffer 0 already staged & visible)
    readA(sA0, P, Xh, Xl);
    readB(sB0, P, Uh, Ul);
    #pragma unroll 1
    for (int it = 0; it < 8; ++it) {
      kstep(sA0, sB0, sA1, sB1, it * 2, true);
      kstep(sA1, sB1, sA0, sB0, it * 2 + 1, it < 7);
    }
  };

  // ---- prologue: stage step 0, drain once
  if constexpr (INLINE_A) inlineA(sA0, 0); else stageFullA(sA0, 0);
  stageFullB(sB0, 0);
  asm volatile("s_waitcnt vmcnt(0) lgkmcnt(0)" ::: "memory");
  __builtin_amdgcn_s_barrier();
  asm volatile("" ::: "memory");

  if (wid & 1) kloop(ic<1>{}); else kloop(ic<0>{});

  #undef SCHED0

  // ---- epilogue: per-row argmin over this wave's 8 col-tiles
  float c2v[4];
  #pragma unroll
  for (int j = 0; j < 4; ++j)
    c2v[j] = c2[ntile * 256 + (j >> 1) * 128 + wn * 32 + (j & 1) * 16 + lrow];
  #pragma unroll
  for (int i = 0; i < 8; ++i) {
    #pragma unroll
    for (int jj = 0; jj < 4; ++jj) {
      float v = FLT_MAX; int idx = 0x7fffffff;
      #pragma unroll
      for (int j = 0; j < 4; ++j) {
        const float sc = c2v[j] - 2.0f * acc[i][j][jj];
        const int col = ntile * 256 + (j >> 1) * 128 + wn * 32 + (j & 1) * 16 + lrow;
        if (sc < v || (sc == v && col < idx)) { v = sc; idx = col; }
      }
      #pragma unroll
      for (int m = 1; m < 16; m <<= 1) {
        const float ov = __shfl_xor(v, m);
        const int oi = __shfl_xor(idx, m);
        if (ov < v || (ov == v && oi < idx)) { v = ov; idx = oi; }
      }
      if (lrow == 0) {
        const int row = mtile * 256 + (i >> 2) * 128 + wm * 64 + (i & 3) * 16 + kgrp * 4 + jj;
        part[(size_t)row * 32 + (ntile * 4 + wn)] =
            make_float2(v, __int_as_float(idx));
      }
    }
  }
}

// Final: reduce 32 partials per row, gather codebook row, write outputs.
__global__ __launch_bounds__(256) void vq_final(
    const float* __restrict__ X, const float* __restrict__ CB,
    const float2* __restrict__ part,
    float* __restrict__ out0, float* __restrict__ out1, float* __restrict__ out2,
    int nsub) {
  const int row = blockIdx.x * 4 + (threadIdx.x >> 6);
  const int l = threadIdx.x & 63;
  float v = FLT_MAX; int idx = 0x7fffffff;
  for (int i = l; i < nsub; i += 64) {
    const float2 p = part[(size_t)row * nsub + i];
    const int pi = __float_as_int(p.y);
    if (p.x < v || (p.x == v && pi < idx)) { v = p.x; idx = pi; }
  }
  #pragma unroll
  for (int m = 1; m < 64; m <<= 1) {
    const float ov = __shfl_xor(v, m);
    const int oi = __shfl_xor(idx, m);
    if (ov < v || (ov == v && oi < idx)) { v = ov; idx = oi; }
  }
  const float4* xr = reinterpret_cast<const float4*>(X + (size_t)row * 512);
  const float4* cr = reinterpret_cast<const float4*>(CB + (size_t)idx * 512);
  float4* q  = reinterpret_cast<float4*>(out0 + (size_t)row * 512);
  float4* ls = reinterpret_cast<float4*>(out1 + (size_t)row * 512);
  #pragma unroll
  for (int p = 0; p < 2; ++p) {
    const int e = l + 64 * p;
    const float4 xv = xr[e], cv = cr[e];
    float4 d4, qv, lv;
    d4.x = cv.x - xv.x; d4.y = cv.y - xv.y; d4.z = cv.z - xv.z; d4.w = cv.w - xv.w;
    qv.x = xv.x + d4.x; qv.y = xv.y + d4.y; qv.z = xv.z + d4.z; qv.w = xv.w + d4.w;
    lv.x = d4.x * d4.x; lv.y = d4.y * d4.y; lv.z = d4.z * d4.z; lv.w = d4.w * d4.w;
    q[e] = qv; ls[e] = lv;
  }
  if (l == 0) out2[row] = (float)idx;
}

extern "C" void kernel_launch(void* const* d_in, const int* in_sizes, int n_in,
                              void* d_out, int out_size, void* d_ws, size_t ws_size,
                              hipStream_t stream) {
  const float* X  = (const float*)d_in[0];   // [M,512] fp32
  const float* CB = (const float*)d_in[1];   // [K,512] fp32
  const int D = 512;
  const int M = in_sizes[0] / D;             // 16384
  const int K = in_sizes[1] / D;             // 2048
  float* out0 = (float*)d_out;               // quantized_ste [M,512]
  float* out1 = out0 + (size_t)M * D;        // loss          [M,512]
  float* out2 = out1 + (size_t)M * D;        // nn_idx (as f32) [M]
  float* out3 = out2 + M;                    // codebook copy [K,512]

  char* ws = (char*)d_ws;
  size_t off = 0;
  u16* Bpan = (u16*)(ws + off); off += (size_t)K * D * 4;     // hi+lo interleaved
  float* c2 = (float*)(ws + off); off += (size_t)K * 4;
  const int nsub = K / 64;                                    // 32
  float2* part = (float2*)(ws + off); off += (size_t)M * nsub * 8;
  u16* Apan = (u16*)(ws + off);
  const size_t need_big = off + (size_t)M * D * 4;
  const bool big = (ws_size >= need_big);

  vq_prep<<<K, 128, 0, stream>>>(CB, Bpan, c2, out3);
  const int nmt = M / 256, nnt = K / 256;
  const int nwg = nmt * nnt;                                  // 512
  if (big) {
    vq_prep<<<M, 128, 0, stream>>>(X, Apan, nullptr, nullptr);
    vq_gemm<0><<<nwg, 512, 0, stream>>>(X, Apan, Bpan, c2, part, nnt);
  } else {
    vq_gemm<1><<<nwg, 512, 0, stream>>>(X, nullptr, Bpan, c2, part, nnt);
  }
  vq_final<<<M / 4, 256, 0, stream>>>(X, CB, part, out0, out1, out2, nsub);
}